// Round 5
// baseline (99.863 us; speedup 1.0000x reference)
//
#include <hip/hip_runtime.h>

#define NROW 8192
#define DIM  128
#define NLBL 512
#define JSPLIT 8
#define NSEG  (JSPLIT * 2)          // column partials: 8 chunks x 2 wave-halves
#define BIGF 1e30f

typedef __attribute__((ext_vector_type(8))) short bf16x8;
typedef __attribute__((ext_vector_type(4))) float f32x4;

// ws layout (bytes):
//   [0, 2 MB)              xb2     : bf16 data, FRAGMENT-MAJOR: group g=row>>4 (512),
//                                    chunk c=0..15 (16B each), slot row&15 -> every MFMA
//                                    fragment load is a contiguous 1KB per wave instr,
//                                    and a 128-row tile is a contiguous 32KB (linear LDS stage)
//   2MB + [0,  32 KB)      sq      : f32 row sq-norms (sorted order, fp32-exact)
//   2MB + [32, 64 KB)      rowBand : u32 = binLo | binHi<<16 (sorted-space label band)
//   2MB + [64, 68 KB)      binStart: 513 i32
//   2MB + [68, 72 KB)      cursor  : 512 u32
//   2MB + [128, 640 KB)    posS    : [NSEG][NROW] f32 partial hardest-pos d^2
//   2MB + [640, 1152 KB)   negS    : [NSEG][NROW] f32 partial hardest-neg d^2

__device__ __forceinline__ unsigned short f2bf(float f) {
    unsigned u = __float_as_uint(f);
    unsigned r = (u + 0x7fffu + ((u >> 16) & 1u)) >> 16;   // RNE
    return (unsigned short)r;
}

// async global->LDS, 16B per lane; LDS dest is wave-uniform base + lane*16
__device__ __forceinline__ void gload_lds16(const void* g, void* l) {
    __builtin_amdgcn_global_load_lds(
        (const __attribute__((address_space(1))) void*)g,
        (__attribute__((address_space(3))) void*)l, 16, 0, 0);
}

// 1 block: histogram labels, prefix-scan to bin starts, init cursors + out.
__global__ __launch_bounds__(1024) void prep_sort(const int* __restrict__ lbl,
                                                  int* __restrict__ binStart,
                                                  unsigned* __restrict__ cursor,
                                                  float* __restrict__ out) {
    __shared__ int hist[NLBL];
    __shared__ int scan[NLBL];
    const int t = threadIdx.x;
    if (t < NLBL) hist[t] = 0;
    __syncthreads();
    #pragma unroll
    for (int k = 0; k < NROW / 1024; k++)
        atomicAdd(&hist[lbl[t + k * 1024]], 1);
    __syncthreads();
    if (t < NLBL) scan[t] = hist[t];
    __syncthreads();
    for (int off = 1; off < NLBL; off <<= 1) {
        int v = 0;
        if (t < NLBL && t >= off) v = scan[t - off];
        __syncthreads();
        if (t < NLBL) scan[t] += v;
        __syncthreads();
    }
    if (t < NLBL) {
        int st = scan[t] - hist[t];          // exclusive prefix
        binStart[t] = st;
        cursor[t]   = (unsigned)st;
    }
    if (t == 0) { binStart[NLBL] = NROW; out[0] = 0.0f; }
}

// 16 lanes per row: bf16-convert + scatter to sorted slot in fragment-major layout,
// fp32 sq-norm, and the row's label band [binStart[l], binStart[l+1]).
__global__ __launch_bounds__(256) void prep_scatter(const float* __restrict__ x,
                                                    const int* __restrict__ lbl,
                                                    const int* __restrict__ binStart,
                                                    unsigned* __restrict__ cursor,
                                                    unsigned short* __restrict__ xb2,
                                                    float* __restrict__ sq,
                                                    unsigned* __restrict__ rowBand) {
    const int t   = threadIdx.x;
    const int row = blockIdx.x * 16 + (t >> 4);
    const int c   = t & 15;                     // 16B chunk of the row
    const float* xr = x + (size_t)row * DIM + c * 8;
    float4 f0 = *(const float4*)xr;
    float4 f1 = *(const float4*)(xr + 4);
    float s = f0.x*f0.x + f0.y*f0.y + f0.z*f0.z + f0.w*f0.w
            + f1.x*f1.x + f1.y*f1.y + f1.z*f1.z + f1.w*f1.w;
    #pragma unroll
    for (int m = 1; m <= 8; m <<= 1) s += __shfl_xor(s, m);   // stays in 16-group
    const int l = lbl[row];
    unsigned p = 0;
    if (c == 0) p = atomicAdd(&cursor[l], 1u);  // sorted destination slot
    p = __shfl((int)p, t & 48);                 // broadcast within the 16-group
    unsigned w0 = (unsigned)f2bf(f0.x) | ((unsigned)f2bf(f0.y) << 16);
    unsigned w1 = (unsigned)f2bf(f0.z) | ((unsigned)f2bf(f0.w) << 16);
    unsigned w2 = (unsigned)f2bf(f1.x) | ((unsigned)f2bf(f1.y) << 16);
    unsigned w3 = (unsigned)f2bf(f1.z) | ((unsigned)f2bf(f1.w) << 16);
    uint4 v = make_uint4(w0, w1, w2, w3);
    *(uint4*)(xb2 + (size_t)(p >> 4) * 2048 + c * 128 + (p & 15) * 8) = v;
    if (c == 0) {
        sq[p] = s;
        rowBand[p] = (unsigned)binStart[l] | ((unsigned)binStart[l + 1] << 16);
    }
}

// Full 8192x8192 Gram, 64 row-panels x 8 col-chunks, 2-phase LDS pipeline (T3-min):
// B tile double-buffered via global_load_lds width-16 (linear 32KB copy thanks to the
// fragment-major layout), stage(jt+1) issued BEFORE compute(jt), one __syncthreads per jt
// (its vmcnt-drain waits on a prefetch that had the whole MFMA phase to land).
// A fragments register-resident; extrema in registers; plain seg-split stores (no atomics).
// Default bid->XCD mapping gives each XCD a fixed jq => its 1MB B-chunk stays L2-resident.
__global__ __launch_bounds__(256, 2) void tile_mfma(const unsigned short* __restrict__ xb2,
                                                    const float* __restrict__ sq,
                                                    const unsigned* __restrict__ rowBand,
                                                    float* __restrict__ posS,
                                                    float* __restrict__ negS) {
    __shared__ unsigned short Bs[2][128 * DIM];   // 2 x 32 KB
    const int bid = blockIdx.x;
    const int rb  = bid >> 3;
    const int jq  = bid & 7;
    const int i0  = rb * 128;
    const int t    = threadIdx.x;
    const int lane = t & 63;
    const int w    = t >> 6;
    const int wrow = (w >> 1) * 64;   // wave 2x2 grid over the 128x128 tile
    const int wcol = (w & 1) * 64;
    const int quad = lane >> 4;
    const int l15  = lane & 15;

    const char* xbB   = (const char*)xb2;
    const int   jbase = jq * 1024;

    // ---- A fragments: 16 contiguous-1KB loads, once per block ----
    bf16x8 af[4][4];
    const int gA = (i0 + wrow) >> 4;
    #pragma unroll
    for (int ti = 0; ti < 4; ti++)
        #pragma unroll
        for (int ks = 0; ks < 4; ks++)
            af[ti][ks] = *(const bf16x8*)(xb2 + (size_t)(gA + ti) * 2048 + (ks * 4 + quad) * 128 + l15 * 8);

    // ---- wave-uniform band envelope per ti (band values NOT kept resident: VGPR diet) ----
    int tiLo[4], tiHi[4];
    #pragma unroll
    for (int ti = 0; ti < 4; ti++) {
        uint4 b4 = *(const uint4*)(rowBand + i0 + wrow + ti * 16 + quad * 4);
        int lo = (int)(b4.x & 0xffffu), hi = (int)(b4.x >> 16);
        lo = min(lo, (int)(b4.y & 0xffffu)); hi = max(hi, (int)(b4.y >> 16));
        lo = min(lo, (int)(b4.z & 0xffffu)); hi = max(hi, (int)(b4.z >> 16));
        lo = min(lo, (int)(b4.w & 0xffffu)); hi = max(hi, (int)(b4.w >> 16));
        int v;
        v = __shfl_xor(lo, 16); lo = min(lo, v);
        v = __shfl_xor(lo, 32); lo = min(lo, v);
        v = __shfl_xor(hi, 16); hi = max(hi, v);
        v = __shfl_xor(hi, 32); hi = max(hi, v);
        tiLo[ti] = __builtin_amdgcn_readfirstlane(lo);
        tiHi[ti] = __builtin_amdgcn_readfirstlane(hi);
    }

    float posm[4][4], negm[4][4];
    #pragma unroll
    for (int ti = 0; ti < 4; ti++)
        #pragma unroll
        for (int r = 0; r < 4; r++) { posm[ti][r] = -BIGF; negm[ti][r] = BIGF; }

    // ---- prologue: stage B tile jt=0 into buf0 (linear 32KB copy) ----
    {
        const char* src = xbB + (size_t)((jbase >> 4)) * 4096;
        #pragma unroll
        for (int i = 0; i < 8; i++)
            gload_lds16(src + i * 4096 + t * 16, (char*)&Bs[0][0] + i * 4096 + w * 1024);
    }
    __syncthreads();   // vmcnt(0) + barrier: buf0 ready

    #pragma unroll 1
    for (int jt = 0; jt < 8; jt++) {
        const int cur = jt & 1;
        const int j0  = jbase + jt * 128;

        // stage NEXT tile first (its latency hides under this jt's compute)
        if (jt < 7) {
            const char* src = xbB + (size_t)(((j0 + 128) >> 4)) * 4096;
            #pragma unroll
            for (int i = 0; i < 8; i++)
                gload_lds16(src + i * 4096 + t * 16, (char*)&Bs[cur ^ 1][0] + i * 4096 + w * 1024);
        }

        float sqj[4];
        #pragma unroll
        for (int tj = 0; tj < 4; tj++) sqj[tj] = sq[j0 + wcol + tj * 16 + l15];

        f32x4 acc[4][4];
        #pragma unroll
        for (int ti = 0; ti < 4; ti++)
            #pragma unroll
            for (int tj = 0; tj < 4; tj++) acc[ti][tj] = (f32x4){0.f, 0.f, 0.f, 0.f};

        const char* bsBase = (const char*)&Bs[cur][0] + (wcol >> 4) * 4096;
        #pragma unroll
        for (int ks = 0; ks < 4; ks++) {
            bf16x8 bfr[4];
            #pragma unroll
            for (int tj = 0; tj < 4; tj++)
                bfr[tj] = *(const bf16x8*)(bsBase + tj * 4096 + (ks * 4 + quad) * 256 + l15 * 16);
            #pragma unroll
            for (int ti = 0; ti < 4; ti++)
                #pragma unroll
                for (int tj = 0; tj < 4; tj++)
                    acc[ti][tj] = __builtin_amdgcn_mfma_f32_16x16x32_bf16(af[ti][ks], bfr[tj], acc[ti][tj], 0, 0, 0);
        }

        // ---- epilogue: band-aware, wave-uniform fast/slow split ----
        #pragma unroll
        for (int ti = 0; ti < 4; ti++) {
            #pragma unroll
            for (int tj = 0; tj < 4; tj++) {
                const int colLo = j0 + wcol + tj * 16;
                if (colLo + 16 <= tiLo[ti] || colLo >= tiHi[ti]) {
                    // no same-label pair possible: pure negatives, 2 ops/elem
                    #pragma unroll
                    for (int r = 0; r < 4; r++) {
                        float sr = fmaf(-2.0f, acc[ti][tj][r], sqj[tj]);
                        negm[ti][r] = fminf(negm[ti][r], sr);
                    }
                } else {
                    // rare path (~4% of sub-tiles): reload this ti's band words
                    uint4 b4 = *(const uint4*)(rowBand + i0 + wrow + ti * 16 + quad * 4);
                    unsigned bnd[4] = {b4.x, b4.y, b4.z, b4.w};
                    const int jcol  = colLo + l15;
                    const int rowg0 = i0 + wrow + ti * 16 + quad * 4;
                    #pragma unroll
                    for (int r = 0; r < 4; r++) {
                        float sr = fmaf(-2.0f, acc[ti][tj][r], sqj[tj]);
                        const int lo = (int)(bnd[r] & 0xffffu);
                        const int hi = (int)(bnd[r] >> 16);
                        bool inb  = (jcol >= lo) && (jcol < hi);   // same label (incl self)
                        bool self = (jcol == rowg0 + r);
                        posm[ti][r] = fmaxf(posm[ti][r], (inb && !self) ? sr : -BIGF);
                        negm[ti][r] = fminf(negm[ti][r], inb ? BIGF : sr);
                    }
                }
            }
        }

        __syncthreads();   // drains prefetch (fully covered by compute) + guards buffer reuse
    }

    // ---- flush: reduce across 16 col-lanes, plain store (no atomics) ----
    const int seg = jq * 2 + (wcol >> 6);   // distinct slot per wave-column half
    #pragma unroll
    for (int ti = 0; ti < 4; ti++)
        #pragma unroll
        for (int r = 0; r < 4; r++) {
            float p = posm[ti][r];
            float n = negm[ti][r];
            #pragma unroll
            for (int m = 8; m >= 1; m >>= 1) {
                p = fmaxf(p, __shfl_xor(p, m));
                n = fminf(n, __shfl_xor(n, m));
            }
            if (l15 == 0) {
                int row = i0 + wrow + ti * 16 + quad * 4 + r;
                float sqi = sq[row];
                posS[seg * NROW + row] = fmaxf(0.0f, sqi + p);   // -BIG => 0 (no positive here)
                negS[seg * NROW + row] = fmaxf(0.0f, sqi + n);   // clamp bf16-noise negatives
            }
        }
}

__global__ __launch_bounds__(256) void tri_final(const float* __restrict__ posS,
                                                 const float* __restrict__ negS,
                                                 const float* __restrict__ margin,
                                                 float* __restrict__ out) {
    int r = blockIdx.x * 256 + threadIdx.x;
    float p = 0.0f, n = BIGF;
    #pragma unroll
    for (int q = 0; q < NSEG; q++) {
        p = fmaxf(p, posS[q * NROW + r]);
        n = fminf(n, negS[q * NROW + r]);
    }
    float m = margin[0];
    float loss = fmaxf(sqrtf(p) - sqrtf(n) + m, 0.0f) * (1.0f / (float)NROW);
    #pragma unroll
    for (int o = 32; o > 0; o >>= 1) loss += __shfl_down(loss, o);
    __shared__ float wsum[4];
    int lane = threadIdx.x & 63, wv = threadIdx.x >> 6;
    if (lane == 0) wsum[wv] = loss;
    __syncthreads();
    if (threadIdx.x == 0) atomicAdd(out, wsum[0] + wsum[1] + wsum[2] + wsum[3]);
}

extern "C" void kernel_launch(void* const* d_in, const int* in_sizes, int n_in,
                              void* d_out, int out_size, void* d_ws, size_t ws_size,
                              hipStream_t stream) {
    const float* x      = (const float*)d_in[0];
    const int*   lbl    = (const int*)d_in[1];
    const float* margin = (const float*)d_in[2];
    float* out = (float*)d_out;

    char* ws = (char*)d_ws;
    unsigned short* xb2 = (unsigned short*)ws;
    float*    sq       = (float*)(ws + (2u << 20));
    unsigned* rowBand  = (unsigned*)(ws + (2u << 20) + (32u << 10));
    int*      binStart = (int*)(ws + (2u << 20) + (64u << 10));
    unsigned* cursor   = (unsigned*)(ws + (2u << 20) + (68u << 10));
    float*    posS     = (float*)(ws + (2u << 20) + (128u << 10));
    float*    negS     = (float*)(ws + (2u << 20) + (640u << 10));

    prep_sort<<<1, 1024, 0, stream>>>(lbl, binStart, cursor, out);
    prep_scatter<<<NROW / 16, 256, 0, stream>>>(x, lbl, binStart, cursor, xb2, sq, rowBand);
    tile_mfma<<<64 * JSPLIT, 256, 0, stream>>>(xb2, sq, rowBand, posS, negS);
    tri_final<<<NROW / 256, 256, 0, stream>>>(posS, negS, margin, out);
}

// Round 8
// 90.084 us; speedup vs baseline: 1.1086x; 1.1086x over previous
//
#include <hip/hip_runtime.h>

#define NROW 8192
#define DIM  128
#define NSEG 16                     // 16 column chunks of 512 cols
#define BIGF 1e30f

typedef __attribute__((ext_vector_type(8))) short bf16x8;
typedef __attribute__((ext_vector_type(4))) float f32x4;

// ws layout (bytes):
//   [0, 2 MB)            xb2  : bf16, FRAGMENT-MAJOR: group g=row>>4 (512 groups),
//                               chunk c=0..15 (16B), slot row&15 -> every MFMA fragment
//                               load is contiguous 1KB/wave; a 64-col tile = linear 16KB
//   2MB + [0, 32 KB)     sq   : f32 row sq-norms (fp32-exact)
//   2MB + [64, 576 KB)   posS : [NSEG][NROW] f32 partial hardest-pos d^2
//   2MB + [576,1088 KB)  negS : [NSEG][NROW] f32 partial hardest-neg d^2

__device__ __forceinline__ unsigned short f2bf(float f) {
    unsigned u = __float_as_uint(f);
    unsigned r = (u + 0x7fffu + ((u >> 16) & 1u)) >> 16;   // RNE
    return (unsigned short)r;
}

// async global->LDS, 16B per lane; LDS dest wave-uniform base + lane*16
__device__ __forceinline__ void gload_lds16(const void* g, void* l) {
    __builtin_amdgcn_global_load_lds(
        (const __attribute__((address_space(1))) void*)g,
        (__attribute__((address_space(3))) void*)l, 16, 0, 0);
}

// one wave per row: bf16-convert into fragment-major layout + fp32 sq-norm
__global__ __launch_bounds__(256) void prep_kernel(const float* __restrict__ x,
                                                   unsigned short* __restrict__ xb2,
                                                   float* __restrict__ sq,
                                                   float* __restrict__ out) {
    int gtid = blockIdx.x * 256 + threadIdx.x;
    if (gtid == 0) out[0] = 0.0f;
    int row  = gtid >> 6;
    int lane = threadIdx.x & 63;
    const float* xr = x + (size_t)row * DIM;
    float a = xr[lane];
    float b = xr[lane + 64];
    // fragment-major dst: g*2048 + chunk*128 + slot*8 + within (ushort units)
    size_t d0 = (size_t)(row >> 4) * 2048 + (size_t)(lane >> 3) * 128
              + (size_t)(row & 15) * 8 + (lane & 7);
    xb2[d0]            = f2bf(a);   // elem lane      -> chunk lane>>3
    xb2[d0 + 8 * 128]  = f2bf(b);   // elem lane+64   -> chunk 8+(lane>>3)
    float s = a * a + b * b;
    #pragma unroll
    for (int o = 32; o > 0; o >>= 1) s += __shfl_down(s, o);
    if (lane == 0) sq[row] = s;
}

// Full Gram, 64 row-panels x 16 col-chunks (1024 blocks = 4/CU). 4 waves STACKED:
// wave w owns rows [i0+w*32, +32) x all 64 cols of each jt tile -> small register
// footprint (acc[2][4]+af[2][4] ~ 140 VGPR) for 3 waves/SIMD occupancy, which is
// the lever this round: every prior variant ran latency-bound at 2 waves/SIMD.
// B double-buffered 2x16KB via linear global_load_lds; A frags register-resident;
// extrema in registers; per-seg plain stores (waves own disjoint rows -> no race).
__global__ __launch_bounds__(256, 3) void tile_mfma(const unsigned short* __restrict__ xb2,
                                                    const int* __restrict__ lbl,
                                                    const float* __restrict__ sq,
                                                    float* __restrict__ posS,
                                                    float* __restrict__ negS) {
    __shared__ unsigned short Bs[2][64 * DIM];   // 2 x 16 KB
    const int bid = blockIdx.x;
    const int rb  = bid >> 4;         // 0..63
    const int jq  = bid & 15;         // 0..15
    const int i0  = rb * 128;
    const int jbase = jq * 512;
    const int t    = threadIdx.x;
    const int lane = t & 63;
    const int w    = t >> 6;
    const int wr0  = i0 + w * 32;     // this wave's first row
    const int quad = lane >> 4;
    const int l15  = lane & 15;

    const char* xbB = (const char*)xb2;

    // ---- A fragments: 8 contiguous-1KB loads, once per block ----
    bf16x8 af[2][4];
    const int gA = wr0 >> 4;
    #pragma unroll
    for (int ti = 0; ti < 2; ti++)
        #pragma unroll
        for (int ks = 0; ks < 4; ks++)
            af[ti][ks] = *(const bf16x8*)(xb2 + (size_t)(gA + ti) * 2048 + (ks * 4 + quad) * 128 + l15 * 8);

    // per-lane row metadata
    int lbli[2][4];
    #pragma unroll
    for (int ti = 0; ti < 2; ti++) {
        int4 l4 = *(const int4*)(lbl + wr0 + ti * 16 + quad * 4);
        lbli[ti][0] = l4.x; lbli[ti][1] = l4.y; lbli[ti][2] = l4.z; lbli[ti][3] = l4.w;
    }
    // does this block's row range intersect its col range? (1 of 16 blocks per rb)
    const bool hasDiag = (i0 >= jbase) && (i0 < jbase + 512);

    float posm[2][4], negm[2][4];
    #pragma unroll
    for (int ti = 0; ti < 2; ti++)
        #pragma unroll
        for (int r = 0; r < 4; r++) { posm[ti][r] = -BIGF; negm[ti][r] = BIGF; }

    // ---- prologue: stage B tile jt=0 (linear 16KB copy) ----
    {
        const char* src = xbB + (size_t)(jbase >> 4) * 4096;
        #pragma unroll
        for (int i = 0; i < 4; i++)
            gload_lds16(src + i * 4096 + t * 16, (char*)&Bs[0][0] + i * 4096 + w * 1024);
    }
    __syncthreads();

    #pragma unroll 1
    for (int jt = 0; jt < 8; jt++) {
        const int cur = jt & 1;
        const int j0  = jbase + jt * 64;

        // prefetch next tile (latency hides under this jt's compute)
        if (jt < 7) {
            const char* src = xbB + (size_t)((j0 + 64) >> 4) * 4096;
            #pragma unroll
            for (int i = 0; i < 4; i++)
                gload_lds16(src + i * 4096 + t * 16, (char*)&Bs[cur ^ 1][0] + i * 4096 + w * 1024);
        }

        float sqj[4]; int lblj[4];
        #pragma unroll
        for (int tj = 0; tj < 4; tj++) {
            int c = j0 + tj * 16 + l15;
            sqj[tj]  = sq[c];
            lblj[tj] = lbl[c];
        }

        f32x4 acc[2][4];
        #pragma unroll
        for (int ti = 0; ti < 2; ti++)
            #pragma unroll
            for (int tj = 0; tj < 4; tj++) acc[ti][tj] = (f32x4){0.f, 0.f, 0.f, 0.f};

        #pragma unroll
        for (int ks = 0; ks < 4; ks++) {
            bf16x8 bfr[4];
            #pragma unroll
            for (int tj = 0; tj < 4; tj++)
                bfr[tj] = *(const bf16x8*)((const char*)&Bs[cur][0] + tj * 4096 + (ks * 4 + quad) * 256 + l15 * 16);
            #pragma unroll
            for (int ti = 0; ti < 2; ti++)
                #pragma unroll
                for (int tj = 0; tj < 4; tj++)
                    acc[ti][tj] = __builtin_amdgcn_mfma_f32_16x16x32_bf16(af[ti][ks], bfr[tj], acc[ti][tj], 0, 0, 0);
        }

        // epilogue: direct label compare (kernel is latency-bound, not VALU-bound)
        #pragma unroll
        for (int ti = 0; ti < 2; ti++) {
            const int rowg = wr0 + ti * 16 + quad * 4;
            #pragma unroll
            for (int tj = 0; tj < 4; tj++) {
                const int jc = j0 + tj * 16 + l15;
                #pragma unroll
                for (int r = 0; r < 4; r++) {
                    float sr = fmaf(-2.0f, acc[ti][tj][r], sqj[tj]);
                    bool same = (lbli[ti][r] == lblj[tj]);
                    bool self = hasDiag && (jc == rowg + r);
                    posm[ti][r] = fmaxf(posm[ti][r], (same && !self) ? sr : -BIGF);
                    negm[ti][r] = fminf(negm[ti][r], same ? BIGF : sr);
                }
            }
        }

        __syncthreads();   // prefetch drained (covered by compute) + guards buffer reuse
    }

    // ---- flush: reduce across the 16 col-lanes, plain store per seg ----
    #pragma unroll
    for (int ti = 0; ti < 2; ti++)
        #pragma unroll
        for (int r = 0; r < 4; r++) {
            float p = posm[ti][r];
            float n = negm[ti][r];
            #pragma unroll
            for (int m = 8; m >= 1; m >>= 1) {
                p = fmaxf(p, __shfl_xor(p, m));
                n = fminf(n, __shfl_xor(n, m));
            }
            if (l15 == 0) {
                int row = wr0 + ti * 16 + quad * 4 + r;
                float sqi = sq[row];
                posS[jq * NROW + row] = fmaxf(0.0f, sqi + p);   // -BIG -> 0 (no positive here)
                negS[jq * NROW + row] = fmaxf(0.0f, sqi + n);   // clamp bf16-noise negatives
            }
        }
}

__global__ __launch_bounds__(256) void tri_final(const float* __restrict__ posS,
                                                 const float* __restrict__ negS,
                                                 const float* __restrict__ margin,
                                                 float* __restrict__ out) {
    int r = blockIdx.x * 256 + threadIdx.x;
    float p = 0.0f, n = BIGF;
    #pragma unroll
    for (int q = 0; q < NSEG; q++) {
        p = fmaxf(p, posS[q * NROW + r]);
        n = fminf(n, negS[q * NROW + r]);
    }
    float m = margin[0];
    float loss = fmaxf(sqrtf(p) - sqrtf(n) + m, 0.0f) * (1.0f / (float)NROW);
    #pragma unroll
    for (int o = 32; o > 0; o >>= 1) loss += __shfl_down(loss, o);
    __shared__ float wsum[4];
    int lane = threadIdx.x & 63, wv = threadIdx.x >> 6;
    if (lane == 0) wsum[wv] = loss;
    __syncthreads();
    if (threadIdx.x == 0) atomicAdd(out, wsum[0] + wsum[1] + wsum[2] + wsum[3]);
}

extern "C" void kernel_launch(void* const* d_in, const int* in_sizes, int n_in,
                              void* d_out, int out_size, void* d_ws, size_t ws_size,
                              hipStream_t stream) {
    const float* x      = (const float*)d_in[0];
    const int*   lbl    = (const int*)d_in[1];
    const float* margin = (const float*)d_in[2];
    float* out = (float*)d_out;

    char* ws = (char*)d_ws;
    unsigned short* xb2 = (unsigned short*)ws;
    float* sq   = (float*)(ws + (2u << 20));
    float* posS = (float*)(ws + (2u << 20) + (64u << 10));
    float* negS = (float*)(ws + (2u << 20) + (576u << 10));

    prep_kernel<<<2048, 256, 0, stream>>>(x, xb2, sq, out);
    tile_mfma<<<64 * NSEG, 256, 0, stream>>>(xb2, lbl, sq, posS, negS);
    tri_final<<<NROW / 256, 256, 0, stream>>>(posS, negS, margin, out);
}